// Round 6
// baseline (677.722 us; speedup 1.0000x reference)
//
#include <hip/hip_runtime.h>
#include <hip/hip_bf16.h>
#include <cstddef>

// MultiHeadedCrossAttention, Round 6.
// B=2, I=2048, J=16, NK=2048, D_MODEL=256, D_HIDDEN=512, H=8, D_K=64.
//
// R4 (pass, 244us fused): 128 VGPR + 128 AGPR = 256 = exact 2-wave/SIMD cap
// -> compiler emits load->wait->MFMA per fragment; every 4-MFMA group pays
// ~220cyc L2 latency -> MfmaUtil 17.9%. R3/R5's cross-iteration rotation
// prefetch failed correctness twice -> abandoned.
// R6: halve live accumulators (stage1 = two 4-frag passes w/ bf16 stash of
// half-0; stage2 = K-side then V-side 4-frag passes) and batch the 4 weight
// frags + 4 A-frags in ARRAYS before the 16 MFMAs of each iteration.
// Plain straight-line bodies, no guards, no cross-iteration state:
// bit-identical accumulation order vs R2/R4.
// pre_kernel R4-VERBATIM.

#define B_  2
#define I_  2048
#define J_  16
#define NK_ 2048
#define DM  256
#define DH  512
#define H_  8
#define DK  64
#define G_  4    // i's per fused block

typedef __attribute__((ext_vector_type(8))) __bf16 bf16x8;
typedef __attribute__((ext_vector_type(4))) float f32x4;
typedef __attribute__((ext_vector_type(8))) unsigned short ushort8;

__device__ inline unsigned short f2bf(float f) {   // RNE float->bf16
  unsigned int u = __builtin_bit_cast(unsigned int, f);
  u += 0x7FFFu + ((u >> 16) & 1u);
  return (unsigned short)(u >> 16);
}

// ---------------------------------------------------------------------------
// Pre-kernel bodies (R2/R4-verbatim)
// ---------------------------------------------------------------------------
template<int N>
__device__ void swz_body(const float* __restrict__ W,
                         unsigned short* __restrict__ Wf, int bid, int t)
{
  const int u  = bid * 256 + t;
  const int l  = u & 63;
  const int fi = u >> 6;
  const int ks = fi & 15;
  const int nt = fi >> 4;
  const int n  = nt * 16 + (l & 15);
  const int k0 = ks * 32 + (l >> 4) * 8;
  unsigned short tmp[8];
  #pragma unroll
  for (int j = 0; j < 8; ++j) tmp[j] = f2bf(W[(size_t)(k0 + j) * N + n]);
  *(ushort8*)&Wf[(size_t)u * 8] = *(const ushort8*)tmp;
}

template<int N, int CPT>
__device__ void proj_body(const float* __restrict__ X,
                          const float* __restrict__ W,
                          float* __restrict__ Y, float* Xs, int bid, int t)
{
  const int row0 = bid * 8;
  {
    const float4* x4 = (const float4*)(X + (size_t)row0 * DM);
    float4* s4 = (float4*)Xs;
    s4[t] = x4[t]; s4[t + 256] = x4[t + 256];
  }
  __syncthreads();

  float acc[8][CPT];
  #pragma unroll
  for (int r = 0; r < 8; ++r)
    #pragma unroll
    for (int u = 0; u < CPT; ++u) acc[r][u] = 0.f;

  const int c0 = t * CPT;
  for (int k = 0; k < DM; k += 4) {
    float4 xv[8];
    #pragma unroll
    for (int r = 0; r < 8; ++r) xv[r] = *(const float4*)&Xs[r * DM + k];
    #pragma unroll
    for (int kk = 0; kk < 4; ++kk) {
      float w[CPT];
      if constexpr (CPT == 2) {
        const float2 wv = *(const float2*)&W[(size_t)(k + kk) * N + c0];
        w[0] = wv.x; w[1] = wv.y;
      } else {
        const float4 wv = *(const float4*)&W[(size_t)(k + kk) * N + c0];
        w[0] = wv.x; w[1] = wv.y; w[2] = wv.z; w[3] = wv.w;
      }
      #pragma unroll
      for (int r = 0; r < 8; ++r) {
        const float xs = ((const float*)&xv[r])[kk];
        #pragma unroll
        for (int u = 0; u < CPT; ++u) acc[r][u] += xs * w[u];
      }
    }
  }
  #pragma unroll
  for (int r = 0; r < 8; ++r)
    #pragma unroll
    for (int u = 0; u < CPT; ++u)
      Y[(size_t)(row0 + r) * N + c0 + u] = acc[r][u];
}

__global__ __launch_bounds__(256) void pre_kernel(
    const float* __restrict__ q, const float* __restrict__ k,
    const float* __restrict__ Wq, const float* __restrict__ Wkv,
    const float* __restrict__ W1, const float* __restrict__ W2,
    float* __restrict__ qh_ws, float* __restrict__ kv_ws,
    unsigned short* __restrict__ W1f, unsigned short* __restrict__ W2f)
{
  __shared__ float Xs[8 * DM];
  const int bid = blockIdx.x;
  const int t = threadIdx.x;
  if (bid < 512)        proj_body<DH, 2>   (q, Wq,  qh_ws, Xs, bid, t);
  else if (bid < 1024)  proj_body<2*DH, 4> (k, Wkv, kv_ws, Xs, bid - 512, t);
  else if (bid < 1152)  swz_body<DH>       (W1, W1f, bid - 1024, t);
  else                  swz_body<2*DH>     (W2, W2f, bid - 1152, t);
}

// ---------------------------------------------------------------------------
// Fused MFMA pos-MLP + gather + attention + out-projection.
// ---------------------------------------------------------------------------
__global__ __launch_bounds__(256, 2) void fused_mfma(
    const float* __restrict__ pos, const int* __restrict__ lidx,
    const float* __restrict__ qh, const float* __restrict__ kv,
    const unsigned short* __restrict__ W1f, const float* __restrict__ b1,
    const unsigned short* __restrict__ W2f, const float* __restrict__ b2,
    const float* __restrict__ Wout, float* __restrict__ out)
{
  __shared__ unsigned short s_a[G_ * 16 * 64 * 8];   // 64 KB, multi-purpose

  const int t    = threadIdx.x;
  const int lane = t & 63;
  const int w    = t >> 6;        // wave 0..3
  const int g    = lane >> 4;     // row-group within C layout
  const int c16  = lane & 15;     // col within 16-tile
  const int bi0  = blockIdx.x * G_;
  const int b    = bi0 >> 11;     // / I_

  // local_idx may be int64 (reference) or int32; detect.
  bool idx64;
  {
    int orv = 0;
    #pragma unroll
    for (int m = 0; m < 16; ++m) orv |= lidx[2 * m + 1];
    idx64 = (orv == 0);
  }

  // ---- stage pos (64 rows x 512 cols) -> s_a in A-frag order (bf16) ----
  #pragma unroll
  for (int it = 0; it < 16; ++it) {
    const int u  = t + it * 256;
    const int fi = u >> 6, ld = u & 63;
    const int mt = fi >> 4, ks = fi & 15;
    const int row = mt * 16 + (ld & 15);
    const int col = ks * 32 + (ld >> 4) * 8;
    const float* src = pos + (size_t)(bi0 * J_ + row) * DH + col;
    const float4 v0 = *(const float4*)src;
    const float4 v1 = *(const float4*)(src + 4);
    unsigned short tmp[8];
    tmp[0] = f2bf(v0.x); tmp[1] = f2bf(v0.y); tmp[2] = f2bf(v0.z); tmp[3] = f2bf(v0.w);
    tmp[4] = f2bf(v1.x); tmp[5] = f2bf(v1.y); tmp[6] = f2bf(v1.z); tmp[7] = f2bf(v1.w);
    *(ushort8*)&s_a[(size_t)u * 8] = *(const ushort8*)tmp;
  }
  __syncthreads();

  const f32x4 zero4 = {0.f, 0.f, 0.f, 0.f};

  // Plain batched 4-frag MFMA pass over the full K range: all 4 weight frags
  // + all 4 A-frags loaded into arrays BEFORE the 16 MFMAs of each ks.
  // No cross-iteration state -> accumulation order identical to R2/R4.
  auto mfma_pass4 = [&](const unsigned short* __restrict__ Wf, int fragbase,
                        f32x4 (&acc)[G_][4]) {
    for (int ks = 0; ks < 16; ++ks) {
      bf16x8 bfr[4];
      #pragma unroll
      for (int f = 0; f < 4; ++f)
        bfr[f] = *(const bf16x8*)&Wf[((size_t)((fragbase + f) * 16 + ks) * 64 + lane) * 8];
      bf16x8 a[G_];
      #pragma unroll
      for (int mt = 0; mt < G_; ++mt)
        a[mt] = *(const bf16x8*)&s_a[((mt * 16 + ks) * 64 + lane) * 8];
      #pragma unroll
      for (int f = 0; f < 4; ++f)
        #pragma unroll
        for (int mt = 0; mt < G_; ++mt)
          acc[mt][f] = __builtin_amdgcn_mfma_f32_16x16x32_bf16(a[mt], bfr[f], acc[mt][f], 0, 0, 0);
    }
  };

  // ---- stage 1: hidden = relu(pos @ W1 + b1); wave w owns cols w*128.. ----
  // Pass A: n-frags w*8+0..3. Stash relu+bias results as packed bf16 (regs)
  // so pos frags in s_a stay intact for pass B. Pass B: frags w*8+4..7.
  unsigned int stash[4][G_][2];   // [f][mt][{r01,r23}] packed bf16 pairs
  {
    f32x4 acc1a[G_][4];
    #pragma unroll
    for (int mt = 0; mt < G_; ++mt)
      #pragma unroll
      for (int f = 0; f < 4; ++f) acc1a[mt][f] = zero4;
    mfma_pass4(W1f, w * 8, acc1a);
    #pragma unroll
    for (int f = 0; f < 4; ++f) {
      const int col  = (w * 8 + f) * 16 + c16;
      const float bb = b1[col];
      #pragma unroll
      for (int mt = 0; mt < G_; ++mt) {
        unsigned short v[4];
        #pragma unroll
        for (int r = 0; r < 4; ++r)
          v[r] = f2bf(fmaxf(acc1a[mt][f][r] + bb, 0.f));
        stash[f][mt][0] = (unsigned int)v[0] | ((unsigned int)v[1] << 16);
        stash[f][mt][1] = (unsigned int)v[2] | ((unsigned int)v[3] << 16);
      }
    }
  }
  f32x4 acc1b[G_][4];
  #pragma unroll
  for (int mt = 0; mt < G_; ++mt)
    #pragma unroll
    for (int f = 0; f < 4; ++f) acc1b[mt][f] = zero4;
  mfma_pass4(W1f, w * 8 + 4, acc1b);

  __syncthreads();   // everyone done reading pos frags

  // ---- scatter both halves into s_a as stage-2 A-frags ----
  // element (m = g*4+r, k = col): frag fi = mt*16 + (col>>5),
  // lane slot = (m) + ((col>>3)&3)*16, byte = col&7.
  #pragma unroll
  for (int f = 0; f < 4; ++f) {
    // half-0 (from stash), col0 = (w*8+f)*16 + c16
    {
      const int col  = (w * 8 + f) * 16 + c16;
      const int ks2  = col >> 5;
      const int lsel = ((col >> 3) & 3) * 16;
      const int bj   = col & 7;
      #pragma unroll
      for (int mt = 0; mt < G_; ++mt)
        #pragma unroll
        for (int r = 0; r < 4; ++r) {
          const unsigned short hv =
              (unsigned short)(stash[f][mt][r >> 1] >> ((r & 1) * 16));
          s_a[((mt * 16 + ks2) * 64 + (g * 4 + r) + lsel) * 8 + bj] = hv;
        }
    }
    // half-1 (from acc1b), col1 = (w*8+4+f)*16 + c16
    {
      const int col  = (w * 8 + 4 + f) * 16 + c16;
      const float bb = b1[col];
      const int ks2  = col >> 5;
      const int lsel = ((col >> 3) & 3) * 16;
      const int bj   = col & 7;
      #pragma unroll
      for (int mt = 0; mt < G_; ++mt)
        #pragma unroll
        for (int r = 0; r < 4; ++r) {
          const float hv = fmaxf(acc1b[mt][f][r] + bb, 0.f);
          s_a[((mt * 16 + ks2) * 64 + (g * 4 + r) + lsel) * 8 + bj] = f2bf(hv);
        }
    }
  }
  __syncthreads();

  // gather indices: j = g*4 + r for each i (=m-tile)
  int idxr[G_][4];
  #pragma unroll
  for (int mt = 0; mt < G_; ++mt)
    #pragma unroll
    for (int r = 0; r < 4; ++r) {
      const int e = (bi0 + mt) * J_ + g * 4 + r;
      idxr[mt][r] = idx64 ? lidx[2 * e] : lidx[e];
    }

  // ---- stage 2 + attention: wave w -> heads 2w, 2w+1; per head a K-side
  // pass (scores+softmax) then a V-side pass (aggregation). ----
  float agg[2][G_][4];   // [pass][i][d-tile]
  #pragma unroll
  for (int p = 0; p < 2; ++p) {
    const int h = 2 * w + p;

    // K-side: pos_k cols h*128 + tt*16 (frags h*8+0..3)
    f32x4 acck[G_][4];
    #pragma unroll
    for (int mt = 0; mt < G_; ++mt)
      #pragma unroll
      for (int tt = 0; tt < 4; ++tt) acck[mt][tt] = zero4;
    mfma_pass4(W2f, h * 8, acck);

    // scores + softmax (C layout: col = c16, row m = g*4 + reg)
    float b2k[4], qv[G_][4];
    #pragma unroll
    for (int tt = 0; tt < 4; ++tt) b2k[tt] = b2[h * 128 + tt * 16 + c16];
    #pragma unroll
    for (int mt = 0; mt < G_; ++mt)
      #pragma unroll
      for (int tt = 0; tt < 4; ++tt)
        qv[mt][tt] = qh[(size_t)(bi0 + mt) * DH + h * 64 + tt * 16 + c16];

    float pj_all[G_][4];
    #pragma unroll
    for (int mt = 0; mt < G_; ++mt) {
      float pj[4];
      #pragma unroll
      for (int r = 0; r < 4; ++r) {
        const float* kvrow = kv + ((size_t)b * NK_ + idxr[mt][r]) * (2 * DH);
        float s = 0.f;
        #pragma unroll
        for (int tt = 0; tt < 4; ++tt) {
          const int d = h * 64 + tt * 16 + c16;
          const float kg = acck[mt][tt][r] + b2k[tt] + kvrow[d];
          s += qv[mt][tt] * kg;
        }
        s += __shfl_xor(s, 1);  s += __shfl_xor(s, 2);
        s += __shfl_xor(s, 4);  s += __shfl_xor(s, 8);      // full q.kg over d
        pj[r] = s * 0.125f;                                  // D_K^-0.5
      }
      float mx = fmaxf(fmaxf(pj[0], pj[1]), fmaxf(pj[2], pj[3]));
      mx = fmaxf(mx, __shfl_xor(mx, 16));
      mx = fmaxf(mx, __shfl_xor(mx, 32));
      float sum = 0.f;
      #pragma unroll
      for (int r = 0; r < 4; ++r) { pj[r] = __expf(pj[r] - mx); sum += pj[r]; }
      sum += __shfl_xor(sum, 16);
      sum += __shfl_xor(sum, 32);
      const float inv = 1.f / sum;
      #pragma unroll
      for (int r = 0; r < 4; ++r) pj_all[mt][r] = pj[r] * inv;
    }

    // V-side: pos_v cols h*128 + 64 + tt*16 (frags h*8+4..7)
    f32x4 accv[G_][4];
    #pragma unroll
    for (int mt = 0; mt < G_; ++mt)
      #pragma unroll
      for (int tt = 0; tt < 4; ++tt) accv[mt][tt] = zero4;
    mfma_pass4(W2f, h * 8 + 4, accv);

    float b2v[4];
    #pragma unroll
    for (int tt = 0; tt < 4; ++tt) b2v[tt] = b2[h * 128 + 64 + tt * 16 + c16];

    #pragma unroll
    for (int mt = 0; mt < G_; ++mt) {
      #pragma unroll
      for (int r = 0; r < 4; ++r) {
        const float* kvrow = kv + ((size_t)b * NK_ + idxr[mt][r]) * (2 * DH);
        #pragma unroll
        for (int tt = 0; tt < 4; ++tt) {
          const int d = h * 64 + tt * 16 + c16;
          accv[mt][tt][r] += b2v[tt] + kvrow[DH + d];   // vg
        }
      }
      #pragma unroll
      for (int tt = 0; tt < 4; ++tt) {
        float a_ = pj_all[mt][0] * accv[mt][tt][0] + pj_all[mt][1] * accv[mt][tt][1]
                 + pj_all[mt][2] * accv[mt][tt][2] + pj_all[mt][3] * accv[mt][tt][3];
        a_ += __shfl_xor(a_, 16);
        a_ += __shfl_xor(a_, 32);
        agg[p][mt][tt] = a_;
      }
    }
  }
  __syncthreads();   // all waves done reading s_a (hidden frags)

  // ---- write agg into s_a overlay: s_agg[i][512] f32 (8 KB) ----
  float* s_agg = (float*)s_a;
  if (g == 0) {
    #pragma unroll
    for (int p = 0; p < 2; ++p) {
      const int h = 2 * w + p;
      #pragma unroll
      for (int mt = 0; mt < G_; ++mt)
        #pragma unroll
        for (int tt = 0; tt < 4; ++tt)
          s_agg[mt * DH + h * 64 + tt * 16 + c16] = agg[p][mt][tt];
    }
  }
  __syncthreads();

  // ---- out = agg @ Wout; wave w sums k-range [w*128, w*128+128) ----
  float* s_part = (float*)s_a + G_ * DH;   // bytes [8KB, 24KB)
  f32x4 oacc[G_];
  #pragma unroll
  for (int i = 0; i < G_; ++i) oacc[i] = zero4;
  for (int c4 = 0; c4 < 32; ++c4) {
    const int c = w * 128 + c4 * 4;
    f32x4 ag[G_];
    #pragma unroll
    for (int i = 0; i < G_; ++i) ag[i] = *(const f32x4*)&s_agg[i * DH + c];
    #pragma unroll
    for (int cc = 0; cc < 4; ++cc) {
      const f32x4 wv = *(const f32x4*)&Wout[(size_t)(c + cc) * DM + lane * 4];
      #pragma unroll
      for (int i = 0; i < G_; ++i) oacc[i] += wv * ag[i][cc];
    }
  }
  #pragma unroll
  for (int i = 0; i < G_; ++i)
    *(f32x4*)&s_part[(w * G_ + i) * DM + lane * 4] = oacc[i];
  __syncthreads();

  #pragma unroll
  for (int i = 0; i < G_; ++i) {
    const float o = s_part[(0 * G_ + i) * DM + t] + s_part[(1 * G_ + i) * DM + t]
                  + s_part[(2 * G_ + i) * DM + t] + s_part[(3 * G_ + i) * DM + t];
    out[(size_t)(bi0 + i) * DM + t] = o;
  }
}

// ---------------------------------------------------------------------------
extern "C" void kernel_launch(void* const* d_in, const int* in_sizes, int n_in,
                              void* d_out, int out_size, void* d_ws, size_t ws_size,
                              hipStream_t stream)
{
  const float* q    = (const float*)d_in[0];
  const float* k    = (const float*)d_in[1];
  const float* pos  = (const float*)d_in[2];
  const int*   lidx = (const int*)d_in[3];
  const float* Wq   = (const float*)d_in[4];
  const float* Wkv  = (const float*)d_in[5];
  const float* W1   = (const float*)d_in[6];
  const float* b1   = (const float*)d_in[7];
  const float* W2   = (const float*)d_in[8];
  const float* b2   = (const float*)d_in[9];
  const float* Wout = (const float*)d_in[10];
  float* out = (float*)d_out;

  // ws: qh 8MB | kv 16MB | W1f 512KB | W2f 1MB
  float* qh_ws = (float*)d_ws;
  float* kv_ws = qh_ws + (size_t)(B_ * I_) * DH;
  unsigned short* W1f = (unsigned short*)(kv_ws + (size_t)(B_ * NK_) * (2 * DH));
  unsigned short* W2f = W1f + (size_t)DH * DH;

  pre_kernel<<<1408, 256, 0, stream>>>(q, k, Wq, Wkv, W1, W2,
                                       qh_ws, kv_ws, W1f, W2f);
  fused_mfma<<<(B_ * I_) / G_, 256, 0, stream>>>(pos, lidx, qh_ws, kv_ws,
                                                 W1f, b1, W2f, b2, Wout, out);
}